// Round 1
// baseline (278.205 us; speedup 1.0000x reference)
//
#include <hip/hip_runtime.h>
#include <cmath>

#define NQ 16
#define NT 8

// One thread per row. B = 1M rows, each row fully independent.
// labels[q] = 1 iff q == lexicographic argmin of (C, q) among queries with the
// same matched target id (equivalent to "first occurrence in stable ascending
// argsort of C"), so no actual sort is required.
__global__ __launch_bounds__(256) void nearest_matcher_kernel(
    const float* __restrict__ pred_logits,
    const float* __restrict__ pred_disp,
    const float* __restrict__ targets,
    float* __restrict__ out_idx,
    float* __restrict__ out_lab,
    int B)
{
    int b = blockIdx.x * blockDim.x + threadIdx.x;
    if (b >= B) return;

    const float BIGF = 1000000.0f;

    // ---- load targets (8 f32, two float4), map exact zeros to sentinel ----
    const float4* tp = (const float4*)(targets + (size_t)b * NT);
    float4 t0 = tp[0];
    float4 t1 = tp[1];
    float tg[NT] = {t0.x, t0.y, t0.z, t0.w, t1.x, t1.y, t1.z, t1.w};
#pragma unroll
    for (int t = 0; t < NT; ++t) tg[t] = (tg[t] == 0.0f) ? BIGF : tg[t];

    // ---- load logits & disparities (16 f32 each, 4x float4) ----
    float lg[NQ], dsp[NQ];
    const float4* lp = (const float4*)(pred_logits + (size_t)b * NQ);
    const float4* dp = (const float4*)(pred_disp + (size_t)b * NQ);
#pragma unroll
    for (int k = 0; k < 4; ++k) {
        float4 v = lp[k];
        lg[4*k+0] = v.x; lg[4*k+1] = v.y; lg[4*k+2] = v.z; lg[4*k+3] = v.w;
        float4 w = dp[k];
        dsp[4*k+0] = w.x; dsp[4*k+1] = w.y; dsp[4*k+2] = w.z; dsp[4*k+3] = w.w;
    }

    // ---- per-query: argmin_t |disp - tgt| (first occurrence on ties), cost C ----
    int   ind[NQ];
    float C[NQ];
#pragma unroll
    for (int n = 0; n < NQ; ++n) {
        float d = dsp[n];
        float best = fabsf(d - tg[0]);
        int bi = 0;
#pragma unroll
        for (int t = 1; t < NT; ++t) {
            float e = fabsf(d - tg[t]);
            if (e < best) { best = e; bi = t; }   // strict <: first occurrence wins
        }
        // correctly-rounded f32 sigmoid via double exp
        float sig = (float)(1.0 / (1.0 + exp(-(double)lg[n])));
        ind[n] = bi;
        C[n] = (-sig) + best;   // f32: cost_class + cost_disp, same op order as ref
    }

    // ---- per-target winner: min (C, n) lexicographic; static indexing only ----
    int win[NT];
#pragma unroll
    for (int t = 0; t < NT; ++t) {
        int w = -1;
        float bc = 3.0e38f;
#pragma unroll
        for (int n = 0; n < NQ; ++n) {
            bool upd = (ind[n] == t) && (C[n] < bc);  // strict <: earliest query wins ties
            bc = upd ? C[n] : bc;
            w  = upd ? n : w;
        }
        win[t] = w;
    }

    // ---- emit outputs (indices as f32 — values 0..7 exact; labels 0/1) ----
    float4 oi[4], ol[4];
    float* oif = (float*)oi;
    float* olf = (float*)ol;
#pragma unroll
    for (int n = 0; n < NQ; ++n) {
        oif[n] = (float)ind[n];
        bool first = false;
#pragma unroll
        for (int t = 0; t < NT; ++t) first = first || (win[t] == n);
        olf[n] = first ? 1.0f : 0.0f;
    }
    float4* po = (float4*)(out_idx + (size_t)b * NQ);
    float4* pl = (float4*)(out_lab + (size_t)b * NQ);
#pragma unroll
    for (int k = 0; k < 4; ++k) { po[k] = oi[k]; pl[k] = ol[k]; }
}

extern "C" void kernel_launch(void* const* d_in, const int* in_sizes, int n_in,
                              void* d_out, int out_size, void* d_ws, size_t ws_size,
                              hipStream_t stream) {
    const float* pred_logits = (const float*)d_in[0];
    const float* pred_disp   = (const float*)d_in[1];
    const float* targets     = (const float*)d_in[2];

    int B = in_sizes[0] / NQ;

    float* out_idx = (float*)d_out;                      // indices [B, NQ] flat, first
    float* out_lab = out_idx + (size_t)B * NQ;           // labels  [B, NQ] flat, second

    const int threads = 256;
    const int blocks  = (B + threads - 1) / threads;
    hipLaunchKernelGGL(nearest_matcher_kernel, dim3(blocks), dim3(threads), 0, stream,
                       pred_logits, pred_disp, targets, out_idx, out_lab, B);
}

// Round 2
// 274.295 us; speedup vs baseline: 1.0143x; 1.0143x over previous
//
#include <hip/hip_runtime.h>
#include <cmath>

#define NQ 16
#define NT 8

// One thread per row. labels[q] = 1 iff q is the lexicographic argmin of
// (C, q) among queries sharing its matched target id (== first occurrence in
// stable ascending argsort of C) — no sort needed.
//
// Numerics: fast path uses __expf sigmoid (err ~5e-7). During per-target
// dedup we track best AND second-best cost; if any group's gap < 1e-4 the
// ordering could be precision-sensitive, and we redo the row with the exact
// double-exp sigmoid (bit-identical to the round-1 kernel that scored
// absmax 0.0). Slow path fires on ~<<1% of rows.
__global__ __launch_bounds__(256) void nearest_matcher_kernel(
    const float* __restrict__ pred_logits,
    const float* __restrict__ pred_disp,
    const float* __restrict__ targets,
    float* __restrict__ out_idx,
    float* __restrict__ out_lab,
    int B)
{
    int b = blockIdx.x * blockDim.x + threadIdx.x;
    if (b >= B) return;

    const float BIGF = 1000000.0f;

    // ---- targets (8 f32), exact zeros -> sentinel ----
    const float4* tp = (const float4*)(targets + (size_t)b * NT);
    float4 t0 = tp[0];
    float4 t1 = tp[1];
    float tg[NT] = {t0.x, t0.y, t0.z, t0.w, t1.x, t1.y, t1.z, t1.w};
#pragma unroll
    for (int t = 0; t < NT; ++t) tg[t] = (tg[t] == 0.0f) ? BIGF : tg[t];

    // ---- logits & disparities (16 f32 each) ----
    float lg[NQ], dsp[NQ];
    const float4* lp = (const float4*)(pred_logits + (size_t)b * NQ);
    const float4* dp = (const float4*)(pred_disp + (size_t)b * NQ);
#pragma unroll
    for (int k = 0; k < 4; ++k) {
        float4 v = lp[k];
        lg[4*k+0] = v.x; lg[4*k+1] = v.y; lg[4*k+2] = v.z; lg[4*k+3] = v.w;
        float4 w = dp[k];
        dsp[4*k+0] = w.x; dsp[4*k+1] = w.y; dsp[4*k+2] = w.z; dsp[4*k+3] = w.w;
    }

    // ---- per-query argmin_t |disp - tgt| (strict <, first occurrence) ----
    int   ind[NQ];
    float cd[NQ];     // cost_disp (exact, no precision concerns)
    float C[NQ];      // total cost, fast sigmoid
#pragma unroll
    for (int n = 0; n < NQ; ++n) {
        float d = dsp[n];
        float best = fabsf(d - tg[0]);
        int bi = 0;
#pragma unroll
        for (int t = 1; t < NT; ++t) {
            float e = fabsf(d - tg[t]);
            if (e < best) { best = e; bi = t; }
        }
        ind[n] = bi;
        cd[n] = best;
        float sig = 1.0f / (1.0f + __expf(-lg[n]));
        C[n] = (-sig) + best;
    }

    // ---- per-target winner, tracking best & 2nd-best for the gap test ----
    int win[NT];
    bool need_slow = false;
#pragma unroll
    for (int t = 0; t < NT; ++t) {
        int w = -1;
        float bc = 3.0e38f, bc2 = 3.0e38f;
#pragma unroll
        for (int n = 0; n < NQ; ++n) {
            bool member = (ind[n] == t);
            bool upd = member && (C[n] < bc);
            bool upd2 = member && !upd && (C[n] < bc2);
            bc2 = upd ? bc : (upd2 ? C[n] : bc2);
            bc  = upd ? C[n] : bc;
            w   = upd ? n : w;
        }
        win[t] = w;
        // gap small enough that fast-sigmoid error (~5e-7) could flip order?
        need_slow = need_slow || ((bc2 - bc) < 1e-4f);
    }

    // ---- rare exact path: correctly-rounded f32 sigmoid via double exp ----
    if (__builtin_expect(need_slow, 0)) {
#pragma unroll
        for (int n = 0; n < NQ; ++n) {
            float sig = (float)(1.0 / (1.0 + exp(-(double)lg[n])));
            C[n] = (-sig) + cd[n];
        }
#pragma unroll
        for (int t = 0; t < NT; ++t) {
            int w = -1;
            float bc = 3.0e38f;
#pragma unroll
            for (int n = 0; n < NQ; ++n) {
                bool upd = (ind[n] == t) && (C[n] < bc);
                bc = upd ? C[n] : bc;
                w  = upd ? n : w;
            }
            win[t] = w;
        }
    }

    // ---- emit: indices as f32 (0..7 exact), labels 0/1 ----
    float4 oi[4], ol[4];
    float* oif = (float*)oi;
    float* olf = (float*)ol;
#pragma unroll
    for (int n = 0; n < NQ; ++n) {
        oif[n] = (float)ind[n];
        bool first = false;
#pragma unroll
        for (int t = 0; t < NT; ++t) first = first || (win[t] == n);
        olf[n] = first ? 1.0f : 0.0f;
    }
    float4* po = (float4*)(out_idx + (size_t)b * NQ);
    float4* pl = (float4*)(out_lab + (size_t)b * NQ);
#pragma unroll
    for (int k = 0; k < 4; ++k) { po[k] = oi[k]; pl[k] = ol[k]; }
}

extern "C" void kernel_launch(void* const* d_in, const int* in_sizes, int n_in,
                              void* d_out, int out_size, void* d_ws, size_t ws_size,
                              hipStream_t stream) {
    const float* pred_logits = (const float*)d_in[0];
    const float* pred_disp   = (const float*)d_in[1];
    const float* targets     = (const float*)d_in[2];

    int B = in_sizes[0] / NQ;

    float* out_idx = (float*)d_out;              // indices [B, NQ] flat, first
    float* out_lab = out_idx + (size_t)B * NQ;   // labels  [B, NQ] flat, second

    const int threads = 256;
    const int blocks  = (B + threads - 1) / threads;
    hipLaunchKernelGGL(nearest_matcher_kernel, dim3(blocks), dim3(threads), 0, stream,
                       pred_logits, pred_disp, targets, out_idx, out_lab, B);
}

// Round 3
// 265.158 us; speedup vs baseline: 1.0492x; 1.0345x over previous
//
#include <hip/hip_runtime.h>
#include <cmath>

#define NQ 16
#define NT 8

// One thread per row. labels[q] = 1 iff q is the lexicographic argmin of
// (C, q) among queries sharing its matched target id (== first occurrence in
// stable ascending argsort of C) — no sort needed.
//
// Numerics: fast path uses __expf sigmoid (err ~5e-7 in C). Per-target dedup
// tracks best and second-best cost; only if a group with >=2 REAL members has
// gap < 1e-4 (100x margin over fast-sigmoid error) do we recompute the row
// with the exact double-exp sigmoid (bit-identical to the round-1 kernel that
// scored absmax 0.0). R2 bug fixed: empty groups (bc==bc2==INF) must NOT
// trigger the slow path — guard with bc2 < 1e37.
__global__ __launch_bounds__(256) void nearest_matcher_kernel(
    const float* __restrict__ pred_logits,
    const float* __restrict__ pred_disp,
    const float* __restrict__ targets,
    float* __restrict__ out_idx,
    float* __restrict__ out_lab,
    int B)
{
    int b = blockIdx.x * blockDim.x + threadIdx.x;
    if (b >= B) return;

    const float BIGF = 1000000.0f;
    const float INF  = 3.0e38f;

    // ---- targets (8 f32), exact zeros -> sentinel ----
    const float4* tp = (const float4*)(targets + (size_t)b * NT);
    float4 t0 = tp[0];
    float4 t1 = tp[1];
    float tg[NT] = {t0.x, t0.y, t0.z, t0.w, t1.x, t1.y, t1.z, t1.w};
#pragma unroll
    for (int t = 0; t < NT; ++t) tg[t] = (tg[t] == 0.0f) ? BIGF : tg[t];

    // ---- logits & disparities (16 f32 each) ----
    float lg[NQ], dsp[NQ];
    const float4* lp = (const float4*)(pred_logits + (size_t)b * NQ);
    const float4* dp = (const float4*)(pred_disp + (size_t)b * NQ);
#pragma unroll
    for (int k = 0; k < 4; ++k) {
        float4 v = lp[k];
        lg[4*k+0] = v.x; lg[4*k+1] = v.y; lg[4*k+2] = v.z; lg[4*k+3] = v.w;
        float4 w = dp[k];
        dsp[4*k+0] = w.x; dsp[4*k+1] = w.y; dsp[4*k+2] = w.z; dsp[4*k+3] = w.w;
    }

    // ---- per-query argmin_t |disp - tgt| (strict <, first occurrence) ----
    int   ind[NQ];
    float cd[NQ];     // cost_disp (exact)
    float C[NQ];      // total cost, fast sigmoid
#pragma unroll
    for (int n = 0; n < NQ; ++n) {
        float d = dsp[n];
        float best = fabsf(d - tg[0]);
        int bi = 0;
#pragma unroll
        for (int t = 1; t < NT; ++t) {
            float e = fabsf(d - tg[t]);
            if (e < best) { best = e; bi = t; }
        }
        ind[n] = bi;
        cd[n] = best;
        float sig = 1.0f / (1.0f + __expf(-lg[n]));
        C[n] = (-sig) + best;
    }

    // ---- per-target winner (min/max trick) + gap detection ----
    // w init = 31: "no winner" shifts into bit 31, which label-read ignores.
    unsigned mask = 0u;
    bool need_slow = false;
#pragma unroll
    for (int t = 0; t < NT; ++t) {
        int w = 31;
        float bc = INF, bc2 = INF;
#pragma unroll
        for (int n = 0; n < NQ; ++n) {
            float x = (ind[n] == t) ? C[n] : INF;
            float hi = fmaxf(bc, x);        // loser of this round
            w   = (x < bc) ? n : w;         // strict <: first query wins ties
            bc  = fminf(bc, x);
            bc2 = fminf(bc2, hi);
        }
        // only meaningful when the group has >=2 real members
        need_slow = need_slow || ((bc2 < 1.0e37f) && (bc2 - bc < 1e-4f));
        mask |= (1u << w);
    }

    // ---- rare exact path: correctly-rounded f32 sigmoid via double exp ----
    if (__builtin_expect(need_slow, 0)) {
#pragma unroll
        for (int n = 0; n < NQ; ++n) {
            float sig = (float)(1.0 / (1.0 + exp(-(double)lg[n])));
            C[n] = (-sig) + cd[n];
        }
        mask = 0u;
#pragma unroll
        for (int t = 0; t < NT; ++t) {
            int w = 31;
            float bc = INF;
#pragma unroll
            for (int n = 0; n < NQ; ++n) {
                bool upd = (ind[n] == t) && (C[n] < bc);
                bc = upd ? C[n] : bc;
                w  = upd ? n : w;
            }
            mask |= (1u << w);
        }
    }

    // ---- emit: indices as f32 (0..7 exact), labels from mask bits ----
    float4 oi[4], ol[4];
    float* oif = (float*)oi;
    float* olf = (float*)ol;
#pragma unroll
    for (int n = 0; n < NQ; ++n) {
        oif[n] = (float)ind[n];
        olf[n] = (float)((mask >> n) & 1u);
    }
    float4* po = (float4*)(out_idx + (size_t)b * NQ);
    float4* pl = (float4*)(out_lab + (size_t)b * NQ);
#pragma unroll
    for (int k = 0; k < 4; ++k) { po[k] = oi[k]; pl[k] = ol[k]; }
}

extern "C" void kernel_launch(void* const* d_in, const int* in_sizes, int n_in,
                              void* d_out, int out_size, void* d_ws, size_t ws_size,
                              hipStream_t stream) {
    const float* pred_logits = (const float*)d_in[0];
    const float* pred_disp   = (const float*)d_in[1];
    const float* targets     = (const float*)d_in[2];

    int B = in_sizes[0] / NQ;

    float* out_idx = (float*)d_out;              // indices [B, NQ] flat, first
    float* out_lab = out_idx + (size_t)B * NQ;   // labels  [B, NQ] flat, second

    const int threads = 256;
    const int blocks  = (B + threads - 1) / threads;
    hipLaunchKernelGGL(nearest_matcher_kernel, dim3(blocks), dim3(threads), 0, stream,
                       pred_logits, pred_disp, targets, out_idx, out_lab, B);
}